// Round 1
// baseline (107.401 us; speedup 1.0000x reference)
//
#include <hip/hip_runtime.h>
#include <math.h>

#define NV 512
#define NF 1024
#define IMS 256
constexpr float SIGMA = 0.003f;

// ---------------- projection: 512 vertices -> 2D NDC ----------------
__global__ void project_kernel(const float* __restrict__ verts, float* __restrict__ xy) {
    int i = blockIdx.x * blockDim.x + threadIdx.x;
    if (i >= NV) return;
    const float deg2rad = 0.017453292519943295f;
    float e = 0.0f * deg2rad;
    float a = 90.0f * deg2rad;
    float ce = cosf(e), se = sinf(e), ca = cosf(a), sa = sinf(a);
    float ex = 2.732f * ce * sa, ey = 2.732f * se, ez = -2.732f * ce * ca;
    // zax = normalize(at - eye) = normalize(-eye)
    float zn = sqrtf(ex*ex + ey*ey + ez*ez) + 1e-12f;
    float zx = -ex/zn, zy = -ey/zn, zz = -ez/zn;
    // xax = normalize(cross(up, zax)), up = (0,1,0)
    float cx = 1.0f*zz - 0.0f*zy;
    float cy = 0.0f*zx - 0.0f*zz;
    float cz = 0.0f*zy - 1.0f*zx;
    float xn = sqrtf(cx*cx + cy*cy + cz*cz) + 1e-12f;
    float xax_x = cx/xn, xax_y = cy/xn, xax_z = cz/xn;
    // yax = cross(zax, xax)
    float yx = zy*xax_z - zz*xax_y;
    float yy = zz*xax_x - zx*xax_z;
    float yz = zx*xax_y - zy*xax_x;
    float w = tanf(30.0f * deg2rad);
    float vx = verts[i*3+0] - ex, vy = verts[i*3+1] - ey, vz = verts[i*3+2] - ez;
    float camx = xax_x*vx + xax_y*vy + xax_z*vz;
    float camy = yx*vx + yy*vy + yz*vz;
    float camz = zx*vx + zy*vy + zz*vz;
    float z = fmaxf(camz, 0.01f);
    float invzw = 1.0f / (z * w);
    xy[i*2+0] = camx * invzw;
    xy[i*2+1] = camy * invzw;
}

// ---------------- per-face edge-line coefficients ----------------
// d_edge(px,py) = A*px + B*py + C, with sign(area), 1/|e| and 1/SIGMA folded in.
__global__ void face_kernel(const float* __restrict__ xy, const int* __restrict__ faces,
                            float* __restrict__ coef) {
    int f = blockIdx.x * blockDim.x + threadIdx.x;
    if (f >= NF) return;
    int i0 = faces[f*3+0], i1 = faces[f*3+1], i2 = faces[f*3+2];
    float ax = xy[i0*2], ay = xy[i0*2+1];
    float bx = xy[i1*2], by = xy[i1*2+1];
    float cx = xy[i2*2], cy = xy[i2*2+1];
    float area = (bx-ax)*(cy-ay) - (by-ay)*(cx-ax);
    float s = (area >= 0.0f) ? 1.0f : -1.0f;
    float pxs[3] = {ax,bx,cx}, pys[3] = {ay,by,cy};
    float o[9];
    #pragma unroll
    for (int k = 0; k < 3; ++k) {
        float x0 = pxs[k],         y0 = pys[k];
        float x1 = pxs[(k+1)%3],   y1 = pys[(k+1)%3];
        float ex_ = x1 - x0, ey_ = y1 - y0;
        float len = sqrtf(ex_*ex_ + ey_*ey_);
        float inv = s * (1.0f/SIGMA) / (len + 1e-12f);
        o[k*3+0] = -ey_ * inv;
        o[k*3+1] =  ex_ * inv;
        o[k*3+2] = (ey_*x0 - ex_*y0) * inv;
    }
    float* dst = coef + f*12;
    #pragma unroll
    for (int k = 0; k < 9; ++k) dst[k] = o[k];
    dst[9] = dst[10] = dst[11] = 0.0f;
}

// ---------------- rasterize + loss ----------------
__global__ __launch_bounds__(256) void raster_kernel(const float* __restrict__ coef,
                                                     const float* __restrict__ img,
                                                     float* __restrict__ out) {
    int pix = blockIdx.x * 256 + threadIdx.x;
    int i = pix >> 8, j = pix & 255;
    float px = ((float)j + 0.5f) * (2.0f/(float)IMS) - 1.0f;
    float py = -(((float)i + 0.5f) * (2.0f/(float)IMS) - 1.0f);
    float prod = 1.0f;
    const float4* c4 = (const float4*)coef;
    for (int f = 0; f < NF; ++f) {
        float4 c0 = c4[f*3+0];
        float4 c1 = c4[f*3+1];
        float4 c2 = c4[f*3+2];
        float d0 = fmaf(c0.x, px, fmaf(c0.y, py, c0.z));
        float d1 = fmaf(c0.w, px, fmaf(c1.x, py, c1.y));
        float d2 = fmaf(c1.z, px, fmaf(c1.w, py, c2.x));
        float t = fminf(d0, fminf(d1, d2));
        // 1 - sigmoid(t) = 1/(1+exp(t)); inf-safe: exp->inf => factor 0
        float ef = __expf(t);
        prod *= __builtin_amdgcn_rcpf(1.0f + ef);
    }
    float sil = 1.0f - prod;
    float diff = sil - img[pix];
    float v = diff * diff;
    // wave (64) reduce
    #pragma unroll
    for (int o = 32; o > 0; o >>= 1) v += __shfl_down(v, o);
    __shared__ float red[4];
    if ((threadIdx.x & 63) == 0) red[threadIdx.x >> 6] = v;
    __syncthreads();
    if (threadIdx.x == 0) atomicAdd(out, red[0] + red[1] + red[2] + red[3]);
}

extern "C" void kernel_launch(void* const* d_in, const int* in_sizes, int n_in,
                              void* d_out, int out_size, void* d_ws, size_t ws_size,
                              hipStream_t stream) {
    const float* verts = (const float*)d_in[0];
    const float* img   = (const float*)d_in[1];
    const int*   faces = (const int*)d_in[2];
    float* out = (float*)d_out;
    float* ws  = (float*)d_ws;
    float* xy   = ws;          // 1024 floats
    float* coef = ws + 1024;   // 12288 floats, 16B-aligned

    hipMemsetAsync(out, 0, sizeof(float), stream);
    project_kernel<<<2, 256, 0, stream>>>(verts, xy);
    face_kernel<<<4, 256, 0, stream>>>(xy, faces, coef);
    raster_kernel<<<256, 256, 0, stream>>>(coef, img, out);
}

// Round 2
// 54.816 us; speedup vs baseline: 1.9593x; 1.9593x over previous
//
#include <hip/hip_runtime.h>
#include <math.h>

#define NV 512
#define NF 1024
#define IMS 256
#define CHUNKS 8
#define FPC (NF / CHUNKS)   // 128 faces per chunk
constexpr float SIGMA = 0.003f;
constexpr float LOG2E = 1.4426950408889634f;

#if __has_builtin(__builtin_amdgcn_exp2f)
#define EXP2(x) __builtin_amdgcn_exp2f(x)
#else
#define EXP2(x) exp2f(x)
#endif

// ---------------- projection: 512 vertices -> 2D NDC ----------------
__global__ void project_kernel(const float* __restrict__ verts, float* __restrict__ xy) {
    int i = blockIdx.x * blockDim.x + threadIdx.x;
    if (i >= NV) return;
    const float deg2rad = 0.017453292519943295f;
    float e = 0.0f * deg2rad;
    float a = 90.0f * deg2rad;
    float ce = cosf(e), se = sinf(e), ca = cosf(a), sa = sinf(a);
    float ex = 2.732f * ce * sa, ey = 2.732f * se, ez = -2.732f * ce * ca;
    float zn = sqrtf(ex*ex + ey*ey + ez*ez) + 1e-12f;
    float zx = -ex/zn, zy = -ey/zn, zz = -ez/zn;
    float cx = 1.0f*zz - 0.0f*zy;
    float cy = 0.0f*zx - 0.0f*zz;
    float cz = 0.0f*zy - 1.0f*zx;
    float xn = sqrtf(cx*cx + cy*cy + cz*cz) + 1e-12f;
    float xax_x = cx/xn, xax_y = cy/xn, xax_z = cz/xn;
    float yx = zy*xax_z - zz*xax_y;
    float yy = zz*xax_x - zx*xax_z;
    float yz = zx*xax_y - zy*xax_x;
    float w = tanf(30.0f * deg2rad);
    float vx = verts[i*3+0] - ex, vy = verts[i*3+1] - ey, vz = verts[i*3+2] - ez;
    float camx = xax_x*vx + xax_y*vy + xax_z*vz;
    float camy = yx*vx + yy*vy + yz*vz;
    float camz = zx*vx + zy*vy + zz*vz;
    float z = fmaxf(camz, 0.01f);
    float invzw = 1.0f / (z * w);
    xy[i*2+0] = camx * invzw;
    xy[i*2+1] = camy * invzw;
}

// ---------------- per-face edge-line coefficients ----------------
// d_edge(px,py) = A*px + B*py + C with sign(area), 1/|e|, 1/SIGMA and log2(e)
// folded in, so the factor is rcp(1 + exp2(min_edges(d))).
__global__ void face_kernel(const float* __restrict__ xy, const int* __restrict__ faces,
                            float* __restrict__ coef) {
    int f = blockIdx.x * blockDim.x + threadIdx.x;
    if (f >= NF) return;
    int i0 = faces[f*3+0], i1 = faces[f*3+1], i2 = faces[f*3+2];
    float ax = xy[i0*2], ay = xy[i0*2+1];
    float bx = xy[i1*2], by = xy[i1*2+1];
    float cx = xy[i2*2], cy = xy[i2*2+1];
    float area = (bx-ax)*(cy-ay) - (by-ay)*(cx-ax);
    float s = (area >= 0.0f) ? 1.0f : -1.0f;
    float pxs[3] = {ax,bx,cx}, pys[3] = {ay,by,cy};
    float o[9];
    #pragma unroll
    for (int k = 0; k < 3; ++k) {
        float x0 = pxs[k],       y0 = pys[k];
        float x1 = pxs[(k+1)%3], y1 = pys[(k+1)%3];
        float ex_ = x1 - x0, ey_ = y1 - y0;
        float len = sqrtf(ex_*ex_ + ey_*ey_);
        float inv = s * (LOG2E / SIGMA) / (len + 1e-12f);
        o[k*3+0] = -ey_ * inv;
        o[k*3+1] =  ex_ * inv;
        o[k*3+2] = (ey_*x0 - ex_*y0) * inv;
    }
    float* dst = coef + f*12;
    #pragma unroll
    for (int k = 0; k < 9; ++k) dst[k] = o[k];
    dst[9] = dst[10] = dst[11] = 0.0f;
}

// ---------------- partial products over a face chunk ----------------
__global__ __launch_bounds__(256) void raster_partial(const float* __restrict__ coef,
                                                      float* __restrict__ partial) {
    int pix = blockIdx.x * 256 + threadIdx.x;
    int chunk = blockIdx.y;
    int i = pix >> 8, j = pix & 255;
    float px = ((float)j + 0.5f) * (2.0f/(float)IMS) - 1.0f;
    float py = -(((float)i + 0.5f) * (2.0f/(float)IMS) - 1.0f);
    const float4* c4 = (const float4*)coef + (size_t)chunk * FPC * 3;
    float pa = 1.0f, pb = 1.0f;
    for (int f = 0; f < FPC; f += 8) {
        #pragma unroll
        for (int u = 0; u < 8; ++u) {
            float4 c0 = c4[(f+u)*3+0];
            float4 c1 = c4[(f+u)*3+1];
            float4 c2 = c4[(f+u)*3+2];
            float d0 = fmaf(c0.x, px, fmaf(c0.y, py, c0.z));
            float d1 = fmaf(c0.w, px, fmaf(c1.x, py, c1.y));
            float d2 = fmaf(c1.z, px, fmaf(c1.w, py, c2.x));
            float t = fminf(d0, fminf(d1, d2));
            float ef = EXP2(t);                       // overflow -> inf
            float fac = __builtin_amdgcn_rcpf(1.0f + ef); // rcp(inf) -> 0
            if (u & 1) pb *= fac; else pa *= fac;
        }
        // product is monotone non-increasing; once the whole wave is at
        // exactly 0 no later face can change the result.
        if (__ballot(fmaxf(pa, pb) > 0.0f) == 0ull) break;
    }
    partial[(size_t)chunk * (IMS*IMS) + pix] = pa * pb;
}

// ---------------- combine partials + loss ----------------
__global__ __launch_bounds__(256) void combine_kernel(const float* __restrict__ partial,
                                                      const float* __restrict__ img,
                                                      float* __restrict__ out) {
    int pix = blockIdx.x * 256 + threadIdx.x;
    float prod = 1.0f;
    #pragma unroll
    for (int c = 0; c < CHUNKS; ++c) prod *= partial[(size_t)c * (IMS*IMS) + pix];
    float sil = 1.0f - prod;
    float diff = sil - img[pix];
    float v = diff * diff;
    #pragma unroll
    for (int o = 32; o > 0; o >>= 1) v += __shfl_down(v, o);
    __shared__ float red[4];
    if ((threadIdx.x & 63) == 0) red[threadIdx.x >> 6] = v;
    __syncthreads();
    if (threadIdx.x == 0) atomicAdd(out, red[0] + red[1] + red[2] + red[3]);
}

extern "C" void kernel_launch(void* const* d_in, const int* in_sizes, int n_in,
                              void* d_out, int out_size, void* d_ws, size_t ws_size,
                              hipStream_t stream) {
    const float* verts = (const float*)d_in[0];
    const float* img   = (const float*)d_in[1];
    const int*   faces = (const int*)d_in[2];
    float* out = (float*)d_out;
    float* ws  = (float*)d_ws;
    float* xy      = ws;              // 1024 floats
    float* coef    = ws + 1024;       // 12288 floats (16B aligned)
    float* partial = ws + 13312;      // 8 * 65536 floats = 2 MB

    hipMemsetAsync(out, 0, sizeof(float), stream);
    project_kernel<<<2, 256, 0, stream>>>(verts, xy);
    face_kernel<<<4, 256, 0, stream>>>(xy, faces, coef);
    raster_partial<<<dim3(256, CHUNKS), 256, 0, stream>>>(coef, partial);
    combine_kernel<<<256, 256, 0, stream>>>(partial, img, out);
}